// Round 1
// baseline (1735.193 us; speedup 1.0000x reference)
//
#include <hip/hip_runtime.h>
#include <hip/hip_bf16.h>

#define VOCAB 4096
#define BB 4
#define LL 2048

typedef __hip_bfloat16 bf16;
typedef __bf16 bf16x8 __attribute__((ext_vector_type(8)));
typedef float f32x4 __attribute__((ext_vector_type(4)));

__device__ __forceinline__ void gload16(const void* g, void* l) {
  __builtin_amdgcn_global_load_lds(
      (const __attribute__((address_space(1))) unsigned int*)g,
      (__attribute__((address_space(3))) unsigned int*)l,
      16, 0, 0);
}

// ---------------- transpose f32 [K][N] -> bf16 [N][K] ----------------
__global__ void transpose_f32_bf16(const float* __restrict__ in,
                                   bf16* __restrict__ out, int K, int N) {
  __shared__ float tile[32][33];
  int bx = blockIdx.x;  // tile along N
  int by = blockIdx.y;  // tile along K
  int x = bx * 32 + threadIdx.x;
#pragma unroll
  for (int i = threadIdx.y; i < 32; i += 8)
    tile[i][threadIdx.x] = in[(size_t)(by * 32 + i) * N + x];
  __syncthreads();
  int k = by * 32 + threadIdx.x;
#pragma unroll
  for (int i = threadIdx.y; i < 32; i += 8)
    out[(size_t)(bx * 32 + i) * K + k] = __float2bfloat16(tile[threadIdx.x][i]);
}

// ---------------- gather-sigmoid + causal mean -> bf16 ctx [B*L][V] ----------------
__global__ void ctx_kernel(const int* __restrict__ idx,
                           const float* __restrict__ Mlog,
                           bf16* __restrict__ ctx) {
  const int V = VOCAB, L = LL;
  int b = blockIdx.x >> 5;       // V/128 = 32 column chunks
  int chunk = blockIdx.x & 31;
  int col = chunk * 128 + threadIdx.x * 2;  // 2 adjacent cols per thread
  __shared__ int sidx[LL];
  for (int t = threadIdx.x; t < L; t += 64) sidx[t] = idx[b * L + t];
  __syncthreads();
  float acc0 = 0.f, acc1 = 0.f;
  const float* base = Mlog + col;
  bf16* outp = ctx + (size_t)b * L * V + col;
  for (int t0 = 0; t0 < L; t0 += 16) {
    float2 v[16];
#pragma unroll
    for (int j = 0; j < 16; ++j) {
      int r = sidx[t0 + j];
      v[j] = *(const float2*)(base + (size_t)r * V);
    }
#pragma unroll
    for (int j = 0; j < 16; ++j) {
      acc0 += 1.f / (1.f + __expf(-v[j].x));
      acc1 += 1.f / (1.f + __expf(-v[j].y));
      float inv = 1.f / (float)(t0 + j + 1);
      __hip_bfloat162 o;
      o.x = __float2bfloat16(acc0 * inv);
      o.y = __float2bfloat16(acc1 * inv);
      *(__hip_bfloat162*)(outp + (size_t)(t0 + j) * V) = o;
    }
  }
}

// ---------------- bf16 GEMM: C[M][N] = A[M][K] * Bt[N][K]^T + bias ----------------
// m97 structure: 128x128 tile, BK=64, global_load_lds(16B), XOR-swizzled LDS
// chunks, 2-barrier K loop, 16x16x32 bf16 MFMA, 4 waves (2x2 of 64x64).
// EPI==0: out = bf16 gelu_exact(C)   EPI==1: out = f32 C
template <int EPI>
__global__ __launch_bounds__(256) void gemm_bt(const bf16* __restrict__ A,
                                               const bf16* __restrict__ Bt,
                                               const float* __restrict__ bias,
                                               void* __restrict__ outv,
                                               int M, int N, int K) {
  constexpr int BK = 64;
  __shared__ __align__(16) bf16 lA[128 * BK];
  __shared__ __align__(16) bf16 lB[128 * BK];
  const int tid = threadIdx.x;
  const int wave = tid >> 6;
  const int lane = tid & 63;
  // XCD-aware bijective swizzle (grid % 8 == 0 for all our launches)
  const int nwg = gridDim.x;
  const int bid = blockIdx.x;
  const int swz = (bid & 7) * (nwg >> 3) + (bid >> 3);
  const int gn = N / 128;
  const int bm0 = (swz / gn) * 128;
  const int bn0 = (swz % gn) * 128;
  const int wm = (wave >> 1) * 64;
  const int wn = (wave & 1) * 64;

  // staging: 1024 16B-chunks per operand tile; swizzled slot p holds source
  // chunk (row = p>>3, kc = (p&7) ^ (row&7))  [read side applies same XOR]
  const bf16* gA[4];
  const bf16* gB[4];
  bf16* lAd[4];
  bf16* lBd[4];
#pragma unroll
  for (int j = 0; j < 4; ++j) {
    int p = j * 256 + wave * 64 + lane;
    int row = p >> 3;
    int kc = (p & 7) ^ (row & 7);
    gA[j] = A + (size_t)(bm0 + row) * K + kc * 8;
    gB[j] = Bt + (size_t)(bn0 + row) * K + kc * 8;
    lAd[j] = lA + (j * 256 + wave * 64) * 8;
    lBd[j] = lB + (j * 256 + wave * 64) * 8;
  }

  f32x4 zero = {0.f, 0.f, 0.f, 0.f};
  f32x4 acc[4][4];
#pragma unroll
  for (int i = 0; i < 4; ++i)
#pragma unroll
    for (int j = 0; j < 4; ++j) acc[i][j] = zero;

  const int rsel = lane & 15;   // row-within-16 for A/B frags, col for C
  const int ksel = lane >> 4;   // k-group

  for (int k0 = 0; k0 < K; k0 += BK) {
#pragma unroll
    for (int j = 0; j < 4; ++j) {
      gload16(gA[j] + k0, lAd[j]);
      gload16(gB[j] + k0, lBd[j]);
    }
    __syncthreads();  // drains vmcnt(0): staged data visible
#pragma unroll
    for (int ks = 0; ks < 2; ++ks) {
      bf16x8 af[4], bfv[4];
#pragma unroll
      for (int mt = 0; mt < 4; ++mt) {
        int row = wm + mt * 16 + rsel;
        int kc = ks * 4 + ksel;
        int chunk = row * 8 + (kc ^ (row & 7));
        af[mt] = *(const bf16x8*)(lA + chunk * 8);
      }
#pragma unroll
      for (int nt = 0; nt < 4; ++nt) {
        int row = wn + nt * 16 + rsel;
        int kc = ks * 4 + ksel;
        int chunk = row * 8 + (kc ^ (row & 7));
        bfv[nt] = *(const bf16x8*)(lB + chunk * 8);
      }
#pragma unroll
      for (int mt = 0; mt < 4; ++mt)
#pragma unroll
        for (int nt = 0; nt < 4; ++nt)
          acc[mt][nt] = __builtin_amdgcn_mfma_f32_16x16x32_bf16(
              af[mt], bfv[nt], acc[mt][nt], 0, 0, 0);
    }
    __syncthreads();  // all reads done before next stage overwrites
  }

  // epilogue; C/D layout: col = lane&15, row = (lane>>4)*4 + reg
  const int cl = lane & 15;
  const int rg = lane >> 4;
#pragma unroll
  for (int mt = 0; mt < 4; ++mt) {
#pragma unroll
    for (int nt = 0; nt < 4; ++nt) {
      int col = bn0 + wn + nt * 16 + cl;
      float bv = bias[col];
#pragma unroll
      for (int r = 0; r < 4; ++r) {
        int grow = bm0 + wm + mt * 16 + rg * 4 + r;
        float v = acc[mt][nt][r] + bv;
        if (EPI == 0) {
          float g = 0.5f * v * (1.f + erff(v * 0.70710678118654752f));
          ((bf16*)outv)[(size_t)grow * N + col] = __float2bfloat16(g);
        } else {
          ((float*)outv)[(size_t)grow * N + col] = v;
        }
      }
    }
  }
}

extern "C" void kernel_launch(void* const* d_in, const int* in_sizes, int n_in,
                              void* d_out, int out_size, void* d_ws,
                              size_t ws_size, hipStream_t stream) {
  const int* idx = (const int*)d_in[0];       // [B,L]
  const float* Mlog = (const float*)d_in[1];  // [V,V]
  const float* W1 = (const float*)d_in[2];    // [V,2V]
  const float* b1 = (const float*)d_in[3];    // [2V]
  const float* W2 = (const float*)d_in[4];    // [2V,V]
  const float* b2 = (const float*)d_in[5];    // [V]
  float* out = (float*)d_out;                 // [B,L,V] f32

  char* ws = (char*)d_ws;
  const size_t MB64 = 64ull << 20;
  bf16* ctx = (bf16*)ws;             // 64 MiB  [8192][4096] (dead after GEMM1)
  bf16* W2t = (bf16*)ws;             // aliases ctx: [4096][8192]
  bf16* W1t = (bf16*)(ws + MB64);    // 64 MiB  [8192][4096]
  bf16* h = (bf16*)(ws + 2 * MB64);  // 128 MiB [8192][8192]
  (void)ws_size;  // needs 256 MiB

  dim3 tb(32, 8);
  // W1^T cast
  transpose_f32_bf16<<<dim3(8192 / 32, 4096 / 32), tb, 0, stream>>>(W1, W1t,
                                                                    4096, 8192);
  // ctx = causal-mean(sigmoid(M)[idx])
  ctx_kernel<<<BB * (VOCAB / 128), 64, 0, stream>>>(idx, Mlog, ctx);
  // h = gelu(ctx @ W1 + b1)  -> bf16
  gemm_bt<0><<<(8192 / 128) * (8192 / 128), 256, 0, stream>>>(
      ctx, W1t, b1, h, 8192, 8192, 4096);
  // W2^T cast (reuses ctx space)
  transpose_f32_bf16<<<dim3(4096 / 32, 8192 / 32), tb, 0, stream>>>(W2, W2t,
                                                                    8192, 4096);
  // out = h @ W2 + b2  -> f32
  gemm_bt<1><<<(8192 / 128) * (4096 / 128), 256, 0, stream>>>(
      h, W2t, b2, out, 8192, 4096, 8192);
}

// Round 2
// 1140.480 us; speedup vs baseline: 1.5215x; 1.5215x over previous
//
#include <hip/hip_runtime.h>
#include <hip/hip_bf16.h>

#define VOCAB 4096
#define BB 4
#define LL 2048
#define SEG 16
#define SEGL 128  // LL/SEG

typedef __hip_bfloat16 bf16;
typedef __bf16 bf16x8 __attribute__((ext_vector_type(8)));
typedef float f32x4 __attribute__((ext_vector_type(4)));

__device__ __forceinline__ void gload16(const void* g, void* l) {
  __builtin_amdgcn_global_load_lds(
      (const __attribute__((address_space(1))) unsigned int*)g,
      (__attribute__((address_space(3))) unsigned int*)l, 16, 0, 0);
}

// ---------------- transpose f32 [K][N] -> bf16 [N][K] ----------------
__global__ void transpose_f32_bf16(const float* __restrict__ in,
                                   bf16* __restrict__ out, int K, int N) {
  __shared__ float tile[32][33];
  int bx = blockIdx.x;  // tile along N
  int by = blockIdx.y;  // tile along K
  int x = bx * 32 + threadIdx.x;
#pragma unroll
  for (int i = threadIdx.y; i < 32; i += 8)
    tile[i][threadIdx.x] = in[(size_t)(by * 32 + i) * N + x];
  __syncthreads();
  int k = by * 32 + threadIdx.x;
#pragma unroll
  for (int i = threadIdx.y; i < 32; i += 8)
    out[(size_t)(bx * 32 + i) * K + k] = __float2bfloat16(tile[threadIdx.x][i]);
}

// -------- ctx pass A: per-segment sigmoid column sums --------
// grid: B * (V/256) * SEG blocks, 256 threads
__global__ void ctx_partial(const int* __restrict__ idx,
                            const float* __restrict__ Mlog,
                            float* __restrict__ segsum) {
  int b = blockIdx.x / (16 * SEG);
  int rem = blockIdx.x % (16 * SEG);
  int chunk = rem / SEG;
  int s = rem % SEG;
  int col = chunk * 256 + threadIdx.x;
  __shared__ int sidx[SEGL];
  if (threadIdx.x < SEGL)
    sidx[threadIdx.x] = idx[b * LL + s * SEGL + threadIdx.x];
  __syncthreads();
  const float* base = Mlog + col;
  float a0 = 0.f, a1 = 0.f, a2 = 0.f, a3 = 0.f;
#pragma unroll 4
  for (int t = 0; t < SEGL; t += 4) {
    float v0 = base[(size_t)sidx[t + 0] * VOCAB];
    float v1 = base[(size_t)sidx[t + 1] * VOCAB];
    float v2 = base[(size_t)sidx[t + 2] * VOCAB];
    float v3 = base[(size_t)sidx[t + 3] * VOCAB];
    a0 += 1.f / (1.f + __expf(-v0));
    a1 += 1.f / (1.f + __expf(-v1));
    a2 += 1.f / (1.f + __expf(-v2));
    a3 += 1.f / (1.f + __expf(-v3));
  }
  segsum[(size_t)blockIdx.x * 256 + threadIdx.x] = (a0 + a1) + (a2 + a3);
}

// -------- ctx pass B: replay segment with offset, write running mean --------
__global__ void ctx_final(const int* __restrict__ idx,
                          const float* __restrict__ Mlog,
                          const float* __restrict__ segsum,
                          bf16* __restrict__ ctx) {
  int b = blockIdx.x / (16 * SEG);
  int rem = blockIdx.x % (16 * SEG);
  int chunk = rem / SEG;
  int s = rem % SEG;
  int col = chunk * 256 + threadIdx.x;
  __shared__ int sidx[SEGL];
  if (threadIdx.x < SEGL)
    sidx[threadIdx.x] = idx[b * LL + s * SEGL + threadIdx.x];
  __syncthreads();
  const float* ss = segsum + (size_t)((b * 16 + chunk) * SEG) * 256 + threadIdx.x;
  float acc = 0.f;
  for (int s2 = 0; s2 < s; ++s2) acc += ss[(size_t)s2 * 256];
  const float* base = Mlog + col;
  bf16* outp = ctx + ((size_t)b * LL + (size_t)s * SEGL) * VOCAB + col;
#pragma unroll 8
  for (int t = 0; t < SEGL; ++t) {
    float v = base[(size_t)sidx[t] * VOCAB];
    acc += 1.f / (1.f + __expf(-v));
    float inv = __fdividef(1.f, (float)(s * SEGL + t + 1));
    outp[(size_t)t * VOCAB] = __float2bfloat16(acc * inv);
  }
}

// ---------------- 256x256 8-phase bf16 GEMM: C = A[M][K] * Bt[N][K]^T + bias
// 512 thr (2x4 waves), BK=64, 128KiB LDS dbuf, chunk-XOR swizzle (0 conflicts),
// counted vmcnt(4) once per K-tile, setprio around MFMA clusters.
// EPI==0: out = bf16 gelu_exact(C)   EPI==1: out = f32 C

// stage one half-tile (128 rows x 64 cols) of A or B into buffer b
#define STG_A(t_, h_, b_)                                              \
  {                                                                    \
    const bf16* s_ = Asrc + (size_t)(h_)*128 * K + (size_t)(t_)*64;    \
    bf16* d_ = sm + (b_)*32768 + (h_)*8192 + wave * 512;               \
    gload16(s_, d_);                                                   \
    gload16(s_ + rowK64, d_ + 4096);                                   \
  }
#define STG_B(t_, h_, b_)                                              \
  {                                                                    \
    const bf16* s_ = Bsrc + (size_t)(h_)*128 * K + (size_t)(t_)*64;    \
    bf16* d_ = sm + (b_)*32768 + 16384 + (h_)*8192 + wave * 512;       \
    gload16(s_, d_);                                                   \
    gload16(s_ + rowK64, d_ + 4096);                                   \
  }

// fragment load: slot = row*8 + (kc ^ (row&7)); row&7 == rsel&7 == xorv
#define LDF(base_, row_, kc_) \
  (*(const bf16x8*)((base_) + (row_)*64 + ((((kc_) ^ xorv)) << 3)))

#define LOAD_A(mh_)                                       \
  _Pragma("unroll") for (int i_ = 0; i_ < 4; ++i_) {      \
    int row_ = (mh_)*128 + wm64 + i_ * 16 + rsel;         \
    af[i_][0] = LDF(Ab, row_, ksel);                      \
    af[i_][1] = LDF(Ab, row_, 4 + ksel);                  \
  }
#define LOAD_B(nh_)                                       \
  _Pragma("unroll") for (int j_ = 0; j_ < 2; ++j_) {      \
    int row_ = (nh_)*128 + wn32 + j_ * 16 + rsel;         \
    bfr[j_][0] = LDF(Bb, row_, ksel);                     \
    bfr[j_][1] = LDF(Bb, row_, 4 + ksel);                 \
  }

#define MFMAQ(mh_, nh_)                                                        \
  _Pragma("unroll") for (int i_ = 0; i_ < 4; ++i_)                             \
      _Pragma("unroll") for (int j_ = 0; j_ < 2; ++j_) {                       \
    f32x4& a_ = acc[(mh_)*4 + i_][(nh_)*2 + j_];                               \
    a_ = __builtin_amdgcn_mfma_f32_16x16x32_bf16(af[i_][0], bfr[j_][0], a_, 0, \
                                                 0, 0);                        \
    a_ = __builtin_amdgcn_mfma_f32_16x16x32_bf16(af[i_][1], bfr[j_][1], a_, 0, \
                                                 0, 0);                        \
  }

#define PHASE(LOADS_, STG_, mh_, nh_)                    \
  {                                                      \
    LOADS_;                                              \
    STG_;                                                \
    __builtin_amdgcn_s_barrier();                        \
    asm volatile("s_waitcnt lgkmcnt(0)" ::: "memory");   \
    __builtin_amdgcn_s_setprio(1);                       \
    MFMAQ(mh_, nh_);                                     \
    __builtin_amdgcn_s_setprio(0);                       \
    __builtin_amdgcn_s_barrier();                        \
  }

template <int EPI>
__global__ __launch_bounds__(512, 2) void gemm256(const bf16* __restrict__ A,
                                                  const bf16* __restrict__ Bt,
                                                  const float* __restrict__ bias,
                                                  void* __restrict__ outv,
                                                  int M, int N, int K) {
  __shared__ __align__(16) bf16 sm[65536];  // 128 KiB: 2 x (A 32KB | B 32KB)
  const int tid = threadIdx.x;
  const int wave = tid >> 6;
  const int lane = tid & 63;
  const int nwg = gridDim.x;
  const int bid = blockIdx.x;
  const int swz = (bid & 7) * (nwg >> 3) + (bid >> 3);  // nwg % 8 == 0
  const int gn = N >> 8;
  const int bm0 = (swz / gn) << 8;
  const int bn0 = (swz % gn) << 8;
  const int wm64 = (wave >> 2) << 6;  // wave_m * 64
  const int wn32 = (wave & 3) << 5;   // wave_n * 32
  const int rsel = lane & 15;
  const int ksel = lane >> 4;
  const int xorv = rsel & 7;

  // staging source: thread covers slots tid and tid+512 of each half-tile;
  // slot p -> row=p>>3, kc=(p&7)^(row&7); for p=tid+512 both row+64 & same kc
  const int r0 = tid >> 3;
  const int kc0 = (tid & 7) ^ (r0 & 7);
  const bf16* Asrc = A + (size_t)(bm0 + r0) * K + kc0 * 8;
  const bf16* Bsrc = Bt + (size_t)(bn0 + r0) * K + kc0 * 8;
  const size_t rowK64 = (size_t)64 * K;
  const int NT = K >> 6;

  f32x4 acc[8][4];
#pragma unroll
  for (int i = 0; i < 8; ++i)
#pragma unroll
    for (int j = 0; j < 4; ++j) acc[i][j] = (f32x4){0.f, 0.f, 0.f, 0.f};

  // prologue: tile0 {A0,B1,A1,B0} -> buf0; tile1 {A0,B1} -> buf1
  STG_A(0, 0, 0);
  STG_B(0, 1, 0);
  STG_A(0, 1, 0);
  STG_B(0, 0, 0);
  STG_A(1, 0, 1);
  STG_B(1, 1, 1);

  bf16x8 af[4][2], bfr[2][2];
  for (int t = 0; t < NT; ++t) {
    const int bc = t & 1;
    const int bo = bc ^ 1;
    const bf16* Ab = sm + bc * 32768;
    const bf16* Bb = Ab + 16384;
    // tile t fully landed; only t+1's {A0,B1} (4 loads) may stay in flight
    if (t + 1 < NT)
      asm volatile("s_waitcnt vmcnt(4)" ::: "memory");
    else
      asm volatile("s_waitcnt vmcnt(0)" ::: "memory");
    __builtin_amdgcn_s_barrier();
    // phase order (mh,nh): (0,0) (0,1) (1,1) (1,0) — operand reuse across
    // phases; restage each region only after its last ds_read + barrier.
    PHASE(LOAD_A(0); LOAD_B(0), if (t + 1 < NT) STG_A(t + 1, 1, bo), 0, 0);
    PHASE(LOAD_B(1), if (t + 1 < NT) STG_B(t + 1, 0, bo), 0, 1);
    PHASE(LOAD_A(1), if (t + 2 < NT) STG_A(t + 2, 0, bc), 1, 1);
    PHASE(LOAD_B(0), if (t + 2 < NT) STG_B(t + 2, 1, bc), 1, 0);
  }

  // epilogue; C/D layout: col = lane&15, row = (lane>>4)*4 + reg
  const int cl = lane & 15;
  const int rg = lane >> 4;
#pragma unroll
  for (int m = 0; m < 8; ++m) {
    int grow = bm0 + ((m >> 2) << 7) + wm64 + ((m & 3) << 4) + rg * 4;
#pragma unroll
    for (int n = 0; n < 4; ++n) {
      int col = bn0 + ((n >> 1) << 7) + wn32 + ((n & 1) << 4) + cl;
      float bv = bias[col];
#pragma unroll
      for (int r = 0; r < 4; ++r) {
        size_t o = (size_t)(grow + r) * N + col;
        float v = acc[m][n][r] + bv;
        if (EPI == 0) {
          float g = 0.5f * v * (1.f + erff(v * 0.70710678118654752f));
          ((bf16*)outv)[o] = __float2bfloat16(g);
        } else {
          ((float*)outv)[o] = v;
        }
      }
    }
  }
}

extern "C" void kernel_launch(void* const* d_in, const int* in_sizes, int n_in,
                              void* d_out, int out_size, void* d_ws,
                              size_t ws_size, hipStream_t stream) {
  const int* idx = (const int*)d_in[0];       // [B,L]
  const float* Mlog = (const float*)d_in[1];  // [V,V]
  const float* W1 = (const float*)d_in[2];    // [V,2V]
  const float* b1 = (const float*)d_in[3];    // [2V]
  const float* W2 = (const float*)d_in[4];    // [2V,V]
  const float* b2 = (const float*)d_in[5];    // [V]
  float* out = (float*)d_out;                 // [B,L,V] f32

  char* ws = (char*)d_ws;
  const size_t MB64 = 64ull << 20;
  bf16* ctx = (bf16*)ws;             // 64 MiB  [8192][4096] (dead after GEMM1)
  bf16* W2t = (bf16*)ws;             // aliases ctx: [4096][8192]
  bf16* W1t = (bf16*)(ws + MB64);    // 64 MiB  [8192][4096]
  bf16* h = (bf16*)(ws + 2 * MB64);  // 128 MiB [8192][8192]
  float* segsum = (float*)h;         // 1 MiB, dead before GEMM1 writes h
  (void)ws_size;

  dim3 tb(32, 8);
  // W1^T cast
  transpose_f32_bf16<<<dim3(8192 / 32, 4096 / 32), tb, 0, stream>>>(W1, W1t,
                                                                    4096, 8192);
  // ctx = causal-mean(sigmoid(M)[idx]), segment-parallel two-pass
  ctx_partial<<<BB * 16 * SEG, 256, 0, stream>>>(idx, Mlog, segsum);
  ctx_final<<<BB * 16 * SEG, 256, 0, stream>>>(idx, Mlog, segsum, ctx);
  // h = gelu(ctx @ W1 + b1)  -> bf16
  gemm256<0><<<(8192 / 256) * (8192 / 256), 512, 0, stream>>>(
      ctx, W1t, b1, h, 8192, 8192, 4096);
  // W2^T cast (reuses ctx space)
  transpose_f32_bf16<<<dim3(4096 / 32, 8192 / 32), tb, 0, stream>>>(W2, W2t,
                                                                    8192, 4096);
  // out = h @ W2 + b2  -> f32
  gemm256<1><<<(8192 / 256) * (4096 / 256), 512, 0, stream>>>(
      h, W2t, b2, out, 8192, 4096, 8192);
}